// Round 11
// baseline (392.095 us; speedup 1.0000x reference)
//
#include <hip/hip_runtime.h>

// ---------------------------------------------------------------------------
// Fused QKV-projection + attention (B=8, C=2048, N=512), fp32 in/out.
// Precision: fp32 -> fp16 hi/lo split. Projections: full 3-term fp16 MFMA.
// Attention logits: 1.5-term (S = qh*kh). Measured absmax 1.71e-3 vs 4.57e-3.
// Round 11: REVERT R10 (volatile/setprio/sched_barrier machinery -43us; m190
// lesson) back to the R9 skeleton, then ONE structural change: KVBLK 32 -> 64
// (two 32-kv sub-tiles per softmax round). Doubles MFMA per serial segment,
// halves barrier/exchange/rescale/P-roundtrip frequency. LDS ~141 KB keeps
// 1 block/CU -> 256-reg budget (the R9 win). V sub1 loaded post-barrier so
// L2 latency hides under exchange+PV0.
// ---------------------------------------------------------------------------

typedef _Float16 half_t;
typedef __attribute__((ext_vector_type(8))) _Float16 half8;
typedef __attribute__((ext_vector_type(4))) _Float16 half4;
typedef __attribute__((ext_vector_type(4))) float    f32x4;

#define MFMA16x32(A_, B_, C_) __builtin_amdgcn_mfma_f32_16x16x32_f16((A_), (B_), (C_), 0, 0, 0)

// barrier that is ALSO a compiler memory fence, without draining vmcnt:
#define LIGHT_BARRIER() asm volatile("s_waitcnt lgkmcnt(0)\n\ts_barrier" ::: "memory")

__device__ __forceinline__ void gload_lds16(const void* g, void* l) {
  __builtin_amdgcn_global_load_lds(
      (const __attribute__((address_space(1))) void*)g,
      (__attribute__((address_space(3))) void*)l, 16, 0, 0);
}

// max-reduce over each 16-lane row via DPP (quad_perm xor1/xor2, row_ror 4/8).
__device__ __forceinline__ float dpp_max16(float x) {
  int t;
  t = __builtin_amdgcn_update_dpp(__float_as_int(x), __float_as_int(x), 0xB1, 0xF, 0xF, false);
  x = fmaxf(x, __int_as_float(t));
  t = __builtin_amdgcn_update_dpp(__float_as_int(x), __float_as_int(x), 0x4E, 0xF, 0xF, false);
  x = fmaxf(x, __int_as_float(t));
  t = __builtin_amdgcn_update_dpp(__float_as_int(x), __float_as_int(x), 0x124, 0xF, 0xF, false);
  x = fmaxf(x, __int_as_float(t));
  t = __builtin_amdgcn_update_dpp(__float_as_int(x), __float_as_int(x), 0x128, 0xF, 0xF, false);
  x = fmaxf(x, __int_as_float(t));
  return x;
}

// ---- split fp32 [rows][cols] -> fp16 [rows][2*cols] = [hi | lo] -------------
__global__ void split_hilo(const float* __restrict__ src, half_t* __restrict__ dst,
                           int rows, int cols) {
  int idx = blockIdx.x * 256 + threadIdx.x;
  int total = rows * cols / 4;
  if (idx >= total) return;
  f32x4 v = ((const f32x4*)src)[idx];
  int e = idx * 4;
  int r = e / cols, c = e % cols;
  half4 h, l;
#pragma unroll
  for (int j = 0; j < 4; ++j) {
    float f = v[j];
    _Float16 hh = (_Float16)f;
    h[j] = hh;
    l[j] = (_Float16)(f - (float)hh);
  }
  *(half4*)&dst[(size_t)r * (2 * cols) + c] = h;
  *(half4*)&dst[(size_t)r * (2 * cols) + c + cols] = l;
}

// ---- projection GEMM (unchanged) ---------------------------------------------
// MODE 2: out[t*512 + m] = f16(val)                       (q/k, hi-only compact)
// MODE 1: out[(t>>5)*16384 + m*32 + (t&31)] = f16(val)    (v kv-blocked)
template <int MODE>
__global__ __launch_bounds__(256) void proj_gemm(
    const half_t* __restrict__ A, const half_t* __restrict__ Bm,
    const float* __restrict__ bias, half_t* __restrict__ out) {
  __shared__ half_t At[128 * 64];
  __shared__ half_t Bt[128 * 64];
  const int tid = threadIdx.x;
  const int lane = tid & 63, wv = tid >> 6;
  const int g = lane >> 4, li = lane & 15;
  const int wm = wv >> 1, wn = wv & 1;
  const int M0 = blockIdx.x * 128, N0 = blockIdx.y * 128;

  const f32x4 kZero = {0.f, 0.f, 0.f, 0.f};
  f32x4 acc[4][4];
#pragma unroll
  for (int i = 0; i < 4; ++i)
#pragma unroll
    for (int j = 0; j < 4; ++j) acc[i][j] = kZero;

  for (int kt = 0; kt < 24; ++kt) {
    const int kc = kt * 64;
    const int ab = kc & 1023;
    const int bb = (kc < 512) ? kc : (kc - 512);
    __syncthreads();
#pragma unroll
    for (int s2 = 0; s2 < 4; ++s2) {
      int bid = tid + 256 * s2;
      int row = bid >> 3, blk = bid & 7;
      half8 va = *(const half8*)&A[(size_t)(M0 + row) * 1024 + ab + blk * 8];
      *(half8*)&At[row * 64 + ((blk ^ (row & 7)) * 8)] = va;
      half8 vb = *(const half8*)&Bm[(size_t)(N0 + row) * 1024 + bb + blk * 8];
      *(half8*)&Bt[row * 64 + ((blk ^ (row & 7)) * 8)] = vb;
    }
    __syncthreads();
#pragma unroll
    for (int kk = 0; kk < 2; ++kk) {
      half8 af[4], bf[4];
#pragma unroll
      for (int i = 0; i < 4; ++i) {
        int ar = wm * 64 + i * 16 + li;
        af[i] = *(const half8*)&At[ar * 64 + (((4 * kk + g) ^ (ar & 7)) * 8)];
        int br = wn * 64 + i * 16 + li;
        bf[i] = *(const half8*)&Bt[br * 64 + (((4 * kk + g) ^ (br & 7)) * 8)];
      }
#pragma unroll
      for (int i = 0; i < 4; ++i)
#pragma unroll
        for (int j = 0; j < 4; ++j) acc[i][j] = MFMA16x32(af[i], bf[j], acc[i][j]);
    }
  }

  if (MODE == 2) {
#pragma unroll
    for (int i = 0; i < 4; ++i) {
      int trow = M0 + wm * 64 + i * 16 + 4 * g;
#pragma unroll
      for (int j = 0; j < 4; ++j) {
        int m = N0 + wn * 64 + j * 16 + li;
        float bs = bias[m];
#pragma unroll
        for (int r = 0; r < 4; ++r) {
          out[(size_t)(trow + r) * 512 + m] = (_Float16)(acc[i][j][r] + bs);
        }
      }
    }
  } else {
#pragma unroll
    for (int i = 0; i < 4; ++i) {
      int m0r = M0 + wm * 64 + i * 16 + 4 * g;
#pragma unroll
      for (int r = 0; r < 4; ++r) {
        int m = m0r + r;
        float bs = bias[m];
#pragma unroll
        for (int j = 0; j < 4; ++j) {
          int tt = N0 + wn * 64 + j * 16 + li;
          out[(size_t)(tt >> 5) * 16384 + (size_t)m * 32 + (tt & 31)] =
              (_Float16)(acc[i][j][r] + bs);
        }
      }
    }
  }
}

// ---- flash attention v11 ----------------------------------------------------
// grid 256 (1 block/CU), 512 threads = 8 waves = 4 pair-groups x 16 q-rows.
// Wave pair: wbit splits kv (QK) and n (PV). KVBLK=64: K tile 64x512h = 64 KB,
// double-buffered via global_load_lds (141 KB LDS total -> 1 block/CU ->
// 256-reg budget). Two 32-kv sub-tiles share ONE softmax round per step.
__global__ __attribute__((amdgpu_flat_work_group_size(512, 512),
                          amdgpu_waves_per_eu(2, 2))) void flash_attn(
    const half_t* __restrict__ qs, const half_t* __restrict__ ks,
    const half_t* __restrict__ vblk, float* __restrict__ outp) {
  __shared__ half_t kt[2][32768];      // 2 x 64 KB K-hi tiles (64 rows x 512 h)
  __shared__ half_t plds[4][16][72];   // P per pair-group [q16][kv64+pad16B]
  __shared__ float  tmx[4][2][16];     // per-step wave row-max [grp][wbit][row]
  __shared__ float  lx[4][16];         // final l exchange [grp][row]

  const int blk0 = blockIdx.x;
  const int logical = (blk0 & 7) * 32 + (blk0 >> 3);   // XCD-chunked (256%8==0)
  const int b  = logical >> 5;                         // batch = XCD
  const int c0 = (logical & 31) * 64;
  const int tid = threadIdx.x;
  const int wv = tid >> 6, lane = tid & 63;
  const int grp = wv >> 1, wbit = wv & 1;
  const int g = lane >> 4, li = lane & 15;
  const int qr0 = c0 + grp * 16;
  const int nh0 = wbit * 256;          // this wave's n-half for PV/output

  const char* kbytes = (const char*)(ks + (size_t)b * 2048 * 512);

  // Q-hi fragments pinned in registers (volatile asm: loaded exactly once):
  const half_t* qrow = qs + (size_t)(b * 2048 + qr0 + li) * 512 + 8 * g;
  half8 qh[16];
#pragma unroll
  for (int c = 0; c < 16; ++c) {
    const half_t* ah = qrow + c * 32;
    asm volatile("global_load_dwordx4 %0, %1, off" : "=v"(qh[c]) : "v"(ah));
  }
  asm volatile("s_waitcnt vmcnt(0)" ::: "memory");

  const f32x4 kZero = {0.f, 0.f, 0.f, 0.f};
  f32x4 o[16];
#pragma unroll
  for (int i = 0; i < 16; ++i) o[i] = kZero;
  float mr[4] = {-3e38f, -3e38f, -3e38f, -3e38f};  // joint running max, rows 4g+r
  float m_li = -3e38f, l_li = 0.f;                 // joint running max/l, row li

  // stage K-hi tile: 64 rows x 1024 B = 4096 16B-segs, 8 per thread.
  auto STAGE = [&](int kv0s, int bufs) {
#pragma unroll
    for (int i2 = 0; i2 < 8; ++i2) {
      int seg = i2 * 512 + tid;
      int r = seg >> 6, bb = seg & 63;
      int bsrc = bb ^ (r & 7);
      gload_lds16(kbytes + (size_t)(kv0s + r) * 1024 + bsrc * 16,
                  (void*)&kt[bufs][seg * 8]);
    }
  };

  STAGE(0, 0);
  __syncthreads();
  int cur = 0;

#pragma unroll 1
  for (int t = 0; t < 32; ++t) {      // 32 steps x 64 kv
    // ---- V prefetch for sub-tile 0 (plain loads; compiler schedules) ----
    const half_t* vtile0 = vblk + ((size_t)(b * 64 + 2 * t)) * 16384 +
                           (size_t)nh0 * 32 + li * 32 + 8 * g;
    half8 vreg0[16];
#pragma unroll
    for (int ns = 0; ns < 16; ++ns) vreg0[ns] = *(const half8*)(vtile0 + ns * 512);

    if (t + 1 < 32) STAGE((t + 1) * 64, cur ^ 1);   // prefetch next K tile

    // ---- QK: S[16q][2x16kv(this wave)] = qh . kh^T, 4 MFMA chains ----
    const half_t* krow0 = &kt[cur][(wbit * 16 + li) * 512];
    const half_t* krow1 = &kt[cur][(32 + wbit * 16 + li) * 512];
    const int swz = li & 7;
    f32x4 s0A = kZero, s0B = kZero, s1A = kZero, s1B = kZero;
#pragma unroll
    for (int c = 0; c < 16; c += 2) {
      int o0 = ((4 * c + g) ^ swz) * 8;
      int o1 = ((4 * c + 4 + g) ^ swz) * 8;
      half8 k00 = *(const half8*)&krow0[o0];
      half8 k01 = *(const half8*)&krow0[o1];
      half8 k10 = *(const half8*)&krow1[o0];
      half8 k11 = *(const half8*)&krow1[o1];
      s0A = MFMA16x32(qh[c], k00, s0A);
      s1A = MFMA16x32(qh[c], k10, s1A);
      s0B = MFMA16x32(qh[c + 1], k01, s0B);
      s1B = MFMA16x32(qh[c + 1], k11, s1B);
    }
    f32x4 sv0 = s0A + s0B;
    f32x4 sv1 = s1A + s1B;

    // ---- per-row max over this wave's 32 kv (both subs); P normalized by it
    float tm[4];
#pragma unroll
    for (int r = 0; r < 4; ++r)
      tm[r] = fmaxf(dpp_max16(sv0[r]), dpp_max16(sv1[r]));
#pragma unroll
    for (int r = 0; r < 4; ++r) {
      float p0 = __expf(sv0[r] - tm[r]);           // <= 1
      float p1 = __expf(sv1[r] - tm[r]);
      plds[grp][4 * g + r][li + 16 * wbit] = (half_t)p0;
      plds[grp][4 * g + r][li + 16 * wbit + 32] = (half_t)p1;
    }
    if (li == 0) {
#pragma unroll
      for (int r = 0; r < 4; ++r) tmx[grp][wbit][4 * g + r] = tm[r];
    }
    LIGHT_BARRIER();   // single exchange point per 64 kv

    // ---- joint max, defer-max (THR=8), pa rescale ----
    f32x4 t0 = *(const f32x4*)&tmx[grp][0][4 * g];
    f32x4 t1 = *(const f32x4*)&tmx[grp][1][4 * g];
    float tA = tmx[grp][0][li], tB = tmx[grp][1][li];
    float tf[4];
#pragma unroll
    for (int r = 0; r < 4; ++r) tf[r] = fmaxf(t0[r], t1[r]);
    int grow = (tf[0] > mr[0] + 8.f) | (tf[1] > mr[1] + 8.f) |
               (tf[2] > mr[2] + 8.f) | (tf[3] > mr[3] + 8.f);
    if (__any(grow)) {
      float al[4];
#pragma unroll
      for (int r = 0; r < 4; ++r) {
        float mn = fmaxf(mr[r], tf[r]);
        al[r] = __expf(mr[r] - mn);
        mr[r] = mn;
      }
      f32x4 av = {al[0], al[1], al[2], al[3]};
#pragma unroll
      for (int i = 0; i < 16; ++i) o[i] *= av;
      float mnli = fmaxf(m_li, fmaxf(tA, tB));
      l_li *= __expf(m_li - mnli);
      m_li = mnli;
    }
    // scale for pa fragments: cols 8g (sub0) / 32+8g (sub1) both map
    // cols 0..15 -> wbit0 (tA), 16..31 -> wbit1 (tB) within each sub:
    float sh = __expf(((g < 2) ? tA : tB) - m_li);   // <= 1 (m_li >= tA,tB)
    half_t sh16 = (half_t)sh;
    half8 pa0 = *(const half8*)&plds[grp][li][8 * g];
    half8 pa1 = *(const half8*)&plds[grp][li][32 + 8 * g];
#pragma unroll
    for (int e = 0; e < 8; ++e) { pa0[e] = pa0[e] * sh16; pa1[e] = pa1[e] * sh16; }

    // l harvested from the scaled pa fragments
    float lp = 0.f;
#pragma unroll
    for (int e = 0; e < 8; ++e) lp += (float)pa0[e] + (float)pa1[e];
    lp += __shfl_xor(lp, 16);
    lp += __shfl_xor(lp, 32);
    l_li += lp;

    // ---- V prefetch for sub-tile 1 (latency hides under PV sub0) ----
    const half_t* vtile1 = vtile0 + 16384;
    half8 vreg1[16];
#pragma unroll
    for (int ns = 0; ns < 16; ++ns) vreg1[ns] = *(const half8*)(vtile1 + ns * 512);

    // ---- PV: two sub-tiles into the same o ----
#pragma unroll
    for (int ns = 0; ns < 16; ++ns) o[ns] = MFMA16x32(pa0, vreg0[ns], o[ns]);
#pragma unroll
    for (int ns = 0; ns < 16; ++ns) o[ns] = MFMA16x32(pa1, vreg1[ns], o[ns]);

    __syncthreads();   // full fence: drain stage (vmcnt0), protect kt/plds/tmx
    cur ^= 1;
  }

  // ---- final normalization: l in li-layout, o rows are 4g+r ----
  if (wbit == 0 && g == 0) lx[grp][li] = l_li;
  __syncthreads();
  float inv[4];
#pragma unroll
  for (int r = 0; r < 4; ++r) inv[r] = 1.0f / (lx[grp][4 * g + r] * 22.62741699796952f);

  float* ob = outp + (size_t)b * 1048576 + qr0 + 4 * g;
#pragma unroll
  for (int ns = 0; ns < 16; ++ns) {
#pragma unroll
    for (int r = 0; r < 4; ++r) {
      ob[(size_t)(nh0 + ns * 16 + li) * 2048 + r] = o[ns][r] * inv[r];
    }
  }
}

// ---------------------------------------------------------------------------
extern "C" void kernel_launch(void* const* d_in, const int* in_sizes, int n_in,
                              void* d_out, int out_size, void* d_ws, size_t ws_size,
                              hipStream_t stream) {
  const float* x  = (const float*)d_in[0];
  const float* Wq = (const float*)d_in[1];
  const float* bq = (const float*)d_in[2];
  const float* Wk = (const float*)d_in[3];
  const float* bk = (const float*)d_in[4];
  const float* Wv = (const float*)d_in[5];
  const float* bv = (const float*)d_in[6];

  half_t* xs  = (half_t*)d_ws;                  // [16384][1024] hi|lo
  half_t* qsb = xs  + (size_t)16384 * 1024;     // [16384][512]  hi only
  half_t* ksb = qsb + (size_t)16384 * 512;      // [16384][512]  hi only
  half_t* vtb = ksb + (size_t)16384 * 512;      // [512 blk][512 n][32 kv]
  half_t* wqs = vtb + (size_t)512 * 16384;      // [512][1024]
  half_t* wks = wqs + (size_t)512 * 1024;
  half_t* wvs = wks + (size_t)512 * 1024;

  split_hilo<<<dim3(16384 * 512 / 4 / 256), 256, 0, stream>>>(x, xs, 16384, 512);
  split_hilo<<<dim3(512 * 512 / 4 / 256), 256, 0, stream>>>(Wq, wqs, 512, 512);
  split_hilo<<<dim3(512 * 512 / 4 / 256), 256, 0, stream>>>(Wk, wks, 512, 512);
  split_hilo<<<dim3(512 * 512 / 4 / 256), 256, 0, stream>>>(Wv, wvs, 512, 512);

  proj_gemm<2><<<dim3(128, 4), 256, 0, stream>>>(xs, wqs, bq, qsb);
  proj_gemm<2><<<dim3(128, 4), 256, 0, stream>>>(xs, wks, bk, ksb);
  proj_gemm<1><<<dim3(4, 128), 256, 0, stream>>>(wvs, xs, bv, vtb);

  flash_attn<<<dim3(256), 512, 0, stream>>>(qsb, ksb, vtb, (float*)d_out);
}

// Round 12
// 344.514 us; speedup vs baseline: 1.1381x; 1.1381x over previous
//
#include <hip/hip_runtime.h>

// ---------------------------------------------------------------------------
// Fused QKV-projection + attention (B=8, C=2048, N=512), fp32 in/out.
// Precision: fp32 -> fp16 hi/lo split. Projections: full 3-term fp16 MFMA.
// Attention logits: 1.5-term (S = qh*kh). Measured absmax 1.71e-3 vs 4.57e-3.
// Round 12: FULL-ROW WAVE OWNERSHIP. R10/R11 lost to R9 by arch-VGPR spills
// (envelope = 128 VGPR + 128 AGPR; R11's 192 VGPR -> +12.5MB scratch). R9's
// residual cost is the pair-exchange serial chain (2 barriers + tmx LDS
// rendezvous per tile). Now each wave owns 16 q-rows x full 32 kv x full n:
// row-max local (DPP), P bounce wave-local (lgkmcnt only, NO barrier), one
// K-stage barrier per tile. Fit: qh 64 + working <=128 VGPR; o[32] = 128 AGPR.
// 4 waves/block, grid 256 (1 block/CU, 1 wave/SIMD) — short chain + 32-wide
// MFMA/load ILP replaces the partner-wave latency cover.
// ---------------------------------------------------------------------------

typedef _Float16 half_t;
typedef __attribute__((ext_vector_type(8))) _Float16 half8;
typedef __attribute__((ext_vector_type(4))) _Float16 half4;
typedef __attribute__((ext_vector_type(4))) float    f32x4;

#define MFMA16x32(A_, B_, C_) __builtin_amdgcn_mfma_f32_16x16x32_f16((A_), (B_), (C_), 0, 0, 0)

// wave-local LDS write->read fence (same wave): order + drain, no barrier.
#define LDS_FENCE() asm volatile("s_waitcnt lgkmcnt(0)" ::: "memory")

__device__ __forceinline__ void gload_lds16(const void* g, void* l) {
  __builtin_amdgcn_global_load_lds(
      (const __attribute__((address_space(1))) void*)g,
      (__attribute__((address_space(3))) void*)l, 16, 0, 0);
}

// max-reduce over each 16-lane row via DPP (quad_perm xor1/xor2, row_ror 4/8).
__device__ __forceinline__ float dpp_max16(float x) {
  int t;
  t = __builtin_amdgcn_update_dpp(__float_as_int(x), __float_as_int(x), 0xB1, 0xF, 0xF, false);
  x = fmaxf(x, __int_as_float(t));
  t = __builtin_amdgcn_update_dpp(__float_as_int(x), __float_as_int(x), 0x4E, 0xF, 0xF, false);
  x = fmaxf(x, __int_as_float(t));
  t = __builtin_amdgcn_update_dpp(__float_as_int(x), __float_as_int(x), 0x124, 0xF, 0xF, false);
  x = fmaxf(x, __int_as_float(t));
  t = __builtin_amdgcn_update_dpp(__float_as_int(x), __float_as_int(x), 0x128, 0xF, 0xF, false);
  x = fmaxf(x, __int_as_float(t));
  return x;
}

// ---- split fp32 [rows][cols] -> fp16 [rows][2*cols] = [hi | lo] -------------
__global__ void split_hilo(const float* __restrict__ src, half_t* __restrict__ dst,
                           int rows, int cols) {
  int idx = blockIdx.x * 256 + threadIdx.x;
  int total = rows * cols / 4;
  if (idx >= total) return;
  f32x4 v = ((const f32x4*)src)[idx];
  int e = idx * 4;
  int r = e / cols, c = e % cols;
  half4 h, l;
#pragma unroll
  for (int j = 0; j < 4; ++j) {
    float f = v[j];
    _Float16 hh = (_Float16)f;
    h[j] = hh;
    l[j] = (_Float16)(f - (float)hh);
  }
  *(half4*)&dst[(size_t)r * (2 * cols) + c] = h;
  *(half4*)&dst[(size_t)r * (2 * cols) + c + cols] = l;
}

// ---- projection GEMM (unchanged) ---------------------------------------------
// MODE 2: out[t*512 + m] = f16(val)                       (q/k, hi-only compact)
// MODE 1: out[(t>>5)*16384 + m*32 + (t&31)] = f16(val)    (v kv-blocked)
template <int MODE>
__global__ __launch_bounds__(256) void proj_gemm(
    const half_t* __restrict__ A, const half_t* __restrict__ Bm,
    const float* __restrict__ bias, half_t* __restrict__ out) {
  __shared__ half_t At[128 * 64];
  __shared__ half_t Bt[128 * 64];
  const int tid = threadIdx.x;
  const int lane = tid & 63, wv = tid >> 6;
  const int g = lane >> 4, li = lane & 15;
  const int wm = wv >> 1, wn = wv & 1;
  const int M0 = blockIdx.x * 128, N0 = blockIdx.y * 128;

  const f32x4 kZero = {0.f, 0.f, 0.f, 0.f};
  f32x4 acc[4][4];
#pragma unroll
  for (int i = 0; i < 4; ++i)
#pragma unroll
    for (int j = 0; j < 4; ++j) acc[i][j] = kZero;

  for (int kt = 0; kt < 24; ++kt) {
    const int kc = kt * 64;
    const int ab = kc & 1023;
    const int bb = (kc < 512) ? kc : (kc - 512);
    __syncthreads();
#pragma unroll
    for (int s2 = 0; s2 < 4; ++s2) {
      int bid = tid + 256 * s2;
      int row = bid >> 3, blk = bid & 7;
      half8 va = *(const half8*)&A[(size_t)(M0 + row) * 1024 + ab + blk * 8];
      *(half8*)&At[row * 64 + ((blk ^ (row & 7)) * 8)] = va;
      half8 vb = *(const half8*)&Bm[(size_t)(N0 + row) * 1024 + bb + blk * 8];
      *(half8*)&Bt[row * 64 + ((blk ^ (row & 7)) * 8)] = vb;
    }
    __syncthreads();
#pragma unroll
    for (int kk = 0; kk < 2; ++kk) {
      half8 af[4], bf[4];
#pragma unroll
      for (int i = 0; i < 4; ++i) {
        int ar = wm * 64 + i * 16 + li;
        af[i] = *(const half8*)&At[ar * 64 + (((4 * kk + g) ^ (ar & 7)) * 8)];
        int br = wn * 64 + i * 16 + li;
        bf[i] = *(const half8*)&Bt[br * 64 + (((4 * kk + g) ^ (br & 7)) * 8)];
      }
#pragma unroll
      for (int i = 0; i < 4; ++i)
#pragma unroll
        for (int j = 0; j < 4; ++j) acc[i][j] = MFMA16x32(af[i], bf[j], acc[i][j]);
    }
  }

  if (MODE == 2) {
#pragma unroll
    for (int i = 0; i < 4; ++i) {
      int trow = M0 + wm * 64 + i * 16 + 4 * g;
#pragma unroll
      for (int j = 0; j < 4; ++j) {
        int m = N0 + wn * 64 + j * 16 + li;
        float bs = bias[m];
#pragma unroll
        for (int r = 0; r < 4; ++r) {
          out[(size_t)(trow + r) * 512 + m] = (_Float16)(acc[i][j][r] + bs);
        }
      }
    }
  } else {
#pragma unroll
    for (int i = 0; i < 4; ++i) {
      int m0r = M0 + wm * 64 + i * 16 + 4 * g;
#pragma unroll
      for (int r = 0; r < 4; ++r) {
        int m = m0r + r;
        float bs = bias[m];
#pragma unroll
        for (int j = 0; j < 4; ++j) {
          int tt = N0 + wn * 64 + j * 16 + li;
          out[(size_t)(tt >> 5) * 16384 + (size_t)m * 32 + (tt & 31)] =
              (_Float16)(acc[i][j][r] + bs);
        }
      }
    }
  }
}

// ---- flash attention v12 ----------------------------------------------------
// grid 256 (1 block/CU), 256 threads = 4 waves, each owning 16 q-rows x full
// 32 kv x full 512 n. K-hi tile (32x512h = 32 KB) double-buffered via
// global_load_lds (pre-swizzled source). Per tile: QK 32 MFMAs -> local DPP
// row-max -> P to wave-local LDS (lgkmcnt fence only) -> defer-max rescale ->
// PV 32 MFMAs (V plain loads, compiler-pipelined) -> ONE __syncthreads.
__global__ __attribute__((amdgpu_flat_work_group_size(256, 256))) void flash_attn(
    const half_t* __restrict__ qs, const half_t* __restrict__ ks,
    const half_t* __restrict__ vblk, float* __restrict__ outp) {
  __shared__ half_t kt[2][16384];      // 2 x 32 KB K-hi tiles (32 rows x 512 h)
  __shared__ half_t plds[4][16][40];   // P per wave [q16][kv32+pad] (80B rows)
  __shared__ float  tmw[4][16];        // per-wave row-max relay (li layout)
  __shared__ float  lx[4][16];         // final l relay [wave][row]

  const int blk0 = blockIdx.x;
  const int logical = (blk0 & 7) * 32 + (blk0 >> 3);   // XCD-chunked (256%8==0)
  const int b  = logical >> 5;                         // batch = XCD
  const int c0 = (logical & 31) * 64;
  const int tid = threadIdx.x;
  const int wv = tid >> 6, lane = tid & 63;
  const int g = lane >> 4, li = lane & 15;
  const int qr0 = c0 + wv * 16;

  const char* kbytes = (const char*)(ks + (size_t)b * 2048 * 512);

  // Q-hi fragments pinned in registers (volatile asm: loaded exactly once):
  const half_t* qrow = qs + (size_t)(b * 2048 + qr0 + li) * 512 + 8 * g;
  half8 qh[16];
#pragma unroll
  for (int c = 0; c < 16; ++c) {
    const half_t* ah = qrow + c * 32;
    asm volatile("global_load_dwordx4 %0, %1, off" : "=v"(qh[c]) : "v"(ah));
  }
  asm volatile("s_waitcnt vmcnt(0)" ::: "memory");

  const f32x4 kZero = {0.f, 0.f, 0.f, 0.f};
  f32x4 o[32];                          // full n=512: 128 accumulator regs
#pragma unroll
  for (int i = 0; i < 32; ++i) o[i] = kZero;
  float mr[4] = {-3e38f, -3e38f, -3e38f, -3e38f};  // running max, rows 4g+r
  float m_li = -3e38f, l_li = 0.f;                 // running max/l, row li

  // stage K-hi tile: 32 rows x 1024 B = 2048 16B-segs, 8 per thread.
  auto STAGE = [&](int kv0s, int bufs) {
#pragma unroll
    for (int i2 = 0; i2 < 8; ++i2) {
      int seg = i2 * 256 + tid;
      int r = seg >> 6, bb = seg & 63;
      int bsrc = bb ^ (r & 7);
      gload_lds16(kbytes + (size_t)(kv0s + r) * 1024 + bsrc * 16,
                  (void*)&kt[bufs][seg * 8]);
    }
  };

  STAGE(0, 0);
  __syncthreads();
  int cur = 0;

#pragma unroll 1
  for (int t = 0; t < 64; ++t) {
    if (t + 1 < 64) STAGE((t + 1) * 32, cur ^ 1);   // prefetch next K tile

    // ---- QK: S[16q][32kv] = qh . kh^T, 4 MFMA chains over rows li / 16+li ----
    const half_t* krow0 = &kt[cur][(size_t)li * 512];
    const half_t* krow1 = &kt[cur][(size_t)(16 + li) * 512];
    const int swz = li & 7;
    f32x4 s0A = kZero, s0B = kZero, s1A = kZero, s1B = kZero;
#pragma unroll
    for (int c = 0; c < 16; c += 2) {
      int of0 = ((4 * c + g) ^ swz) * 8;
      int of1 = ((4 * c + 4 + g) ^ swz) * 8;
      half8 k00 = *(const half8*)&krow0[of0];
      half8 k10 = *(const half8*)&krow1[of0];
      half8 k01 = *(const half8*)&krow0[of1];
      half8 k11 = *(const half8*)&krow1[of1];
      s0A = MFMA16x32(qh[c], k00, s0A);
      s1A = MFMA16x32(qh[c], k10, s1A);
      s0B = MFMA16x32(qh[c + 1], k01, s0B);
      s1B = MFMA16x32(qh[c + 1], k11, s1B);
    }
    f32x4 sv0 = s0A + s0B;               // cols li
    f32x4 sv1 = s1A + s1B;               // cols 16+li

    // ---- local full-row max (DPP, no cross-wave anything) ----
    float tm[4];
#pragma unroll
    for (int r = 0; r < 4; ++r)
      tm[r] = fmaxf(dpp_max16(sv0[r]), dpp_max16(sv1[r]));

    // ---- P = exp(S - tm) <= 1 -> wave-local LDS; relay tm to li-layout ----
#pragma unroll
    for (int r = 0; r < 4; ++r) {
      float p0 = __expf(sv0[r] - tm[r]);
      float p1 = __expf(sv1[r] - tm[r]);
      plds[wv][4 * g + r][li] = (half_t)p0;
      plds[wv][4 * g + r][li + 16] = (half_t)p1;
    }
    if (li == 0) {
#pragma unroll
      for (int r = 0; r < 4; ++r) tmw[wv][4 * g + r] = tm[r];
    }
    LDS_FENCE();   // wave-local write->read ordering; NO barrier

    // ---- defer-max (THR=8): rescale o only when a row max jumps ----
    int grow = (tm[0] > mr[0] + 8.f) | (tm[1] > mr[1] + 8.f) |
               (tm[2] > mr[2] + 8.f) | (tm[3] > mr[3] + 8.f);
    float tli = tmw[wv][li];
    if (__any(grow)) {
      float al[4];
#pragma unroll
      for (int r = 0; r < 4; ++r) {
        float mn = fmaxf(mr[r], tm[r]);
        al[r] = __expf(mr[r] - mn);
        mr[r] = mn;
      }
      f32x4 av = {al[0], al[1], al[2], al[3]};
#pragma unroll
      for (int i = 0; i < 32; ++i) o[i] *= av;
      float mnli = fmaxf(m_li, tli);
      l_li *= __expf(m_li - mnli);
      m_li = mnli;
    }

    // pa = P row li, scaled by exp(tli - m_li) <= e^8 (defer bound)
    float sh = __expf(tli - m_li);
    half_t sh16 = (half_t)sh;
    half8 pa = *(const half8*)&plds[wv][li][8 * g];
#pragma unroll
    for (int e = 0; e < 8; ++e) pa[e] = pa[e] * sh16;

    // l harvested from the scaled pa fragment (xor16/32 sums the 4 g-groups)
    float lp = 0.f;
#pragma unroll
    for (int e = 0; e < 8; ++e) lp += (float)pa[e];
    lp += __shfl_xor(lp, 16);
    lp += __shfl_xor(lp, 32);
    l_li += lp;

    // ---- PV over FULL n: 32 independent MFMAs, V loads compiler-pipelined ----
    const half_t* vtile = vblk + ((size_t)(b * 64 + t)) * 16384 + li * 32 + 8 * g;
#pragma unroll
    for (int ns = 0; ns < 32; ++ns) {
      half8 v0 = *(const half8*)(vtile + ns * 512);
      o[ns] = MFMA16x32(pa, v0, o[ns]);
    }

    __syncthreads();   // the ONE barrier: drain stage (vmcnt0), protect kt
    cur ^= 1;
  }

  // ---- final normalization: l in li-layout, o rows are 4g+r ----
  if (g == 0) lx[wv][li] = l_li;
  __syncthreads();
  float inv[4];
#pragma unroll
  for (int r = 0; r < 4; ++r) inv[r] = 1.0f / (lx[wv][4 * g + r] * 22.62741699796952f);

  float* ob = outp + (size_t)b * 1048576 + qr0 + 4 * g;
#pragma unroll
  for (int ns = 0; ns < 32; ++ns) {
#pragma unroll
    for (int r = 0; r < 4; ++r) {
      ob[(size_t)(ns * 16 + li) * 2048 + r] = o[ns][r] * inv[r];
    }
  }
}

// ---------------------------------------------------------------------------
extern "C" void kernel_launch(void* const* d_in, const int* in_sizes, int n_in,
                              void* d_out, int out_size, void* d_ws, size_t ws_size,
                              hipStream_t stream) {
  const float* x  = (const float*)d_in[0];
  const float* Wq = (const float*)d_in[1];
  const float* bq = (const float*)d_in[2];
  const float* Wk = (const float*)d_in[3];
  const float* bk = (const float*)d_in[4];
  const float* Wv = (const float*)d_in[5];
  const float* bv = (const float*)d_in[6];

  half_t* xs  = (half_t*)d_ws;                  // [16384][1024] hi|lo
  half_t* qsb = xs  + (size_t)16384 * 1024;     // [16384][512]  hi only
  half_t* ksb = qsb + (size_t)16384 * 512;      // [16384][512]  hi only
  half_t* vtb = ksb + (size_t)16384 * 512;      // [512 blk][512 n][32 kv]
  half_t* wqs = vtb + (size_t)512 * 16384;      // [512][1024]
  half_t* wks = wqs + (size_t)512 * 1024;
  half_t* wvs = wks + (size_t)512 * 1024;

  split_hilo<<<dim3(16384 * 512 / 4 / 256), 256, 0, stream>>>(x, xs, 16384, 512);
  split_hilo<<<dim3(512 * 512 / 4 / 256), 256, 0, stream>>>(Wq, wqs, 512, 512);
  split_hilo<<<dim3(512 * 512 / 4 / 256), 256, 0, stream>>>(Wk, wks, 512, 512);
  split_hilo<<<dim3(512 * 512 / 4 / 256), 256, 0, stream>>>(Wv, wvs, 512, 512);

  proj_gemm<2><<<dim3(128, 4), 256, 0, stream>>>(xs, wqs, bq, qsb);
  proj_gemm<2><<<dim3(128, 4), 256, 0, stream>>>(xs, wks, bk, ksb);
  proj_gemm<1><<<dim3(4, 128), 256, 0, stream>>>(wvs, xs, bv, vtb);

  flash_attn<<<dim3(256), 256, 0, stream>>>(qsb, ksb, vtb, (float*)d_out);
}